// Round 4
// baseline (105.837 us; speedup 1.0000x reference)
//
#include <hip/hip_runtime.h>
#include <hip/hip_bf16.h>

// MoE token scatter: out[dest[t], :] = token_hidden[t, :] where
// dest[t] = expert_offsets[expert_idx[t]] + slot_idx[t].
// HIDDEN = 1024 fp32 = 256 float4 per row. Pure memory-bound row permute:
// 268 MB read + 268 MB write; float4-copy ceiling (m13, 6.29 TB/s) = ~85 us.
//
// R1 (1 row/block, plain loads): 101.2 us. R3 (grid-stride + NT): 104.5 us —
// regression; both changes reverted. This round: 4 rows per block, same 256
// threads. The 4 index chains are independent (uniform addrs -> s_load) and
// each thread has 4 independent float4 loads in flight before storing -> 4x
// the MLP of R1, 4x fewer dispatches (16384 blocks).

#define HIDDEN 1024
#define VEC 4                    // floats per thread per row
#define THREADS (HIDDEN / VEC)   // 256
#define RPB 4                    // rows per block (65536 % 4 == 0)

typedef float f32x4 __attribute__((ext_vector_type(4)));

__global__ __launch_bounds__(THREADS) void moe_scatter_kernel(
    const float* __restrict__ token_hidden,
    const int* __restrict__ expert_idx,
    const int* __restrict__ slot_idx,
    const int* __restrict__ expert_offsets,
    float* __restrict__ out,
    int num_tokens) {
    const int t0 = blockIdx.x * RPB;

    // Independent index chains for all RPB rows (uniform -> scalar loads).
    int dest[RPB];
#pragma unroll
    for (int r = 0; r < RPB; ++r) {
        const int t = t0 + r;
        dest[r] = expert_offsets[expert_idx[t]] + slot_idx[t];
    }

    // Issue all RPB vector loads before any store (4x16B in flight/thread).
    f32x4 v[RPB];
#pragma unroll
    for (int r = 0; r < RPB; ++r) {
        const f32x4* __restrict__ src =
            reinterpret_cast<const f32x4*>(token_hidden + (size_t)(t0 + r) * HIDDEN);
        v[r] = src[threadIdx.x];
    }
#pragma unroll
    for (int r = 0; r < RPB; ++r) {
        f32x4* __restrict__ dst =
            reinterpret_cast<f32x4*>(out + (size_t)dest[r] * HIDDEN);
        dst[threadIdx.x] = v[r];
    }
}

extern "C" void kernel_launch(void* const* d_in, const int* in_sizes, int n_in,
                              void* d_out, int out_size, void* d_ws, size_t ws_size,
                              hipStream_t stream) {
    const float* token_hidden   = (const float*)d_in[0];
    const int*   expert_idx     = (const int*)d_in[1];
    const int*   slot_idx       = (const int*)d_in[2];
    const int*   expert_offsets = (const int*)d_in[3];
    float* out = (float*)d_out;

    const int num_tokens = in_sizes[1];  // expert_idx has one entry per token

    moe_scatter_kernel<<<num_tokens / RPB, THREADS, 0, stream>>>(
        token_hidden, expert_idx, slot_idx, expert_offsets, out, num_tokens);
}

// Round 5
// 100.508 us; speedup vs baseline: 1.0530x; 1.0530x over previous
//
#include <hip/hip_runtime.h>
#include <hip/hip_bf16.h>

// MoE token scatter: out[dest[t], :] = token_hidden[t, :] where
// dest[t] = expert_offsets[expert_idx[t]] + slot_idx[t].
// HIDDEN = 1024 fp32 = 256 float4 per row. Pure streaming permute:
// 268 MB read + 268 MB write; float4-copy ceiling (m13, 6.29 TB/s) = ~85 us.
//
// Ladder: R1 1-row/256t-block = 101.2 us (5.31 TB/s). R3 grid-stride+NT =
// 104.5 (rev). R4 4-rows-per-thread-batch = 105.8 (rev). This round: same
// per-thread structure as R1 (1 float4 load + 1 store, nothing else), but
// 1024-thread blocks with one row per 256-thread slice -> 4x fewer
// dispatches (16384). Isolates CP dispatch overhead as the last variable.

#define HIDDEN 1024
#define VEC 4                     // floats per thread
#define SLICE (HIDDEN / VEC)      // 256 threads per row
#define RPB 4                     // rows per block
#define THREADS (SLICE * RPB)     // 1024

typedef float f32x4 __attribute__((ext_vector_type(4)));

__global__ __launch_bounds__(THREADS) void moe_scatter_kernel(
    const float* __restrict__ token_hidden,
    const int* __restrict__ expert_idx,
    const int* __restrict__ slot_idx,
    const int* __restrict__ expert_offsets,
    float* __restrict__ out) {
    const int slice = threadIdx.x >> 8;    // which row of this block (0..3)
    const int lane  = threadIdx.x & 255;   // float4 index within the row

    const int t    = blockIdx.x * RPB + slice;
    const int dest = expert_offsets[expert_idx[t]] + slot_idx[t];

    const f32x4* __restrict__ src =
        reinterpret_cast<const f32x4*>(token_hidden + (size_t)t * HIDDEN);
    f32x4* __restrict__ dst =
        reinterpret_cast<f32x4*>(out + (size_t)dest * HIDDEN);

    dst[lane] = src[lane];
}

extern "C" void kernel_launch(void* const* d_in, const int* in_sizes, int n_in,
                              void* d_out, int out_size, void* d_ws, size_t ws_size,
                              hipStream_t stream) {
    const float* token_hidden   = (const float*)d_in[0];
    const int*   expert_idx     = (const int*)d_in[1];
    const int*   slot_idx       = (const int*)d_in[2];
    const int*   expert_offsets = (const int*)d_in[3];
    float* out = (float*)d_out;

    const int num_tokens = in_sizes[1];  // expert_idx has one entry per token

    moe_scatter_kernel<<<num_tokens / RPB, THREADS, 0, stream>>>(
        token_hidden, expert_idx, slot_idx, expert_offsets, out);
}